// Round 4
// baseline (308.312 us; speedup 1.0000x reference)
//
#include <hip/hip_runtime.h>

#define NHEADS 16
#define DEMBED 1024
#define DCROSS 768
#define DHEAD  64
#define BATCH  4
#define SLEN   2048
#define MROWS  (BATCH * SLEN)   // 8192

using bf16   = __bf16;
using bf16x8 = __attribute__((ext_vector_type(8))) __bf16;
using bf16x4 = __attribute__((ext_vector_type(4))) __bf16;
using f32x4  = __attribute__((ext_vector_type(4))) float;

__device__ __forceinline__ f32x4 mfma_bf16(bf16x8 a, bf16x8 b, f32x4 c) {
    return __builtin_amdgcn_mfma_f32_16x16x32_bf16(a, b, c, 0, 0, 0);
}

// async global->LDS, 16B per lane; lds dest = wave-uniform base + lane*16
__device__ __forceinline__ void gl2lds16(const void* g, void* l) {
    __builtin_amdgcn_global_load_lds(
        (const __attribute__((address_space(1))) void*)g,
        (__attribute__((address_space(3))) void*)l, 16, 0, 0);
}

// ---------------------------------------------------------------- prep (fused)
// cvt x and y f32->bf16 in one launch
__global__ void cvt_xy(const float* __restrict__ x, const float* __restrict__ y,
                       bf16* __restrict__ xb, bf16* __restrict__ yb) {
    const int n4x = MROWS * DEMBED / 4;
    const int n4y = MROWS * DCROSS / 4;
    int i = blockIdx.x * blockDim.x + threadIdx.x;
    const float* src;
    bf16* dst;
    int j;
    if (i < n4x) { src = x; dst = xb; j = i; }
    else { j = i - n4x; if (j >= n4y) return; src = y; dst = yb; }
    float4 v = ((const float4*)src)[j];
    bf16x4 o = { (bf16)v.x, (bf16)v.y, (bf16)v.z, (bf16)v.w };
    ((bf16x4*)dst)[j] = o;
}

// all 4 weight transposes in one launch: W [K,1024] f32 -> Wt [1024,K] bf16
struct TrArgs { const float* src[4]; bf16* dst[4]; int K[4]; };
__global__ void transpose_all(TrArgs a) {
    __shared__ float tile[32][33];
    const int which = blockIdx.z;
    const int K = a.K[which];
    const int N = DEMBED;
    int n0 = blockIdx.x * 32, k0 = blockIdx.y * 32;
    if (k0 >= K) return;
    const float* W = a.src[which];
    bf16* Wt = a.dst[which];
    int tx = threadIdx.x, ty = threadIdx.y;
#pragma unroll
    for (int i = 0; i < 32; i += 8)
        tile[ty + i][tx] = W[(size_t)(k0 + ty + i) * N + n0 + tx];
    __syncthreads();
#pragma unroll
    for (int i = 0; i < 32; i += 8)
        Wt[(size_t)(n0 + ty + i) * K + k0 + tx] = (bf16)tile[tx][ty + i];
}

// ---------------------------------------------------------------- GEMM (m97-style)
// C[M,N] = alpha*(A[M,K](bf16) @ Wt[N,K]^T(bf16) + bias).  128x128 tile, BK=32,
// global_load_lds width=16 staging, XOR-swizzled LDS (conflict-free frags).
template <bool F32OUT>
__global__ __launch_bounds__(256, 3) void gemm_bt(const bf16* __restrict__ A,
                                                  const bf16* __restrict__ Bt,
                                                  const float* __restrict__ bias,
                                                  void* __restrict__ Cout,
                                                  int M, int N, int K, float alpha) {
    __shared__ bf16 As[128 * 32];
    __shared__ bf16 Bs[128 * 32];
    const int tid  = threadIdx.x;
    const int wave = tid >> 6, lane = tid & 63;
    const int quad = lane >> 4, l15 = lane & 15;
    const int m0 = blockIdx.x * 128, n0 = blockIdx.y * 128;
    const int wr = wave >> 1, wc = wave & 1;

    const int trow = tid >> 2;
    const int tcol = ((tid & 3) ^ ((tid >> 3) & 3)) * 8;
    char* ldsA0 = (char*)As + wave * 1024;
    char* ldsB0 = (char*)Bs + wave * 1024;
    const bf16* gA0 = A + (size_t)(m0 + trow) * K + tcol;
    const bf16* gA1 = A + (size_t)(m0 + 64 + trow) * K + tcol;
    const bf16* gB0 = Bt + (size_t)(n0 + trow) * K + tcol;
    const bf16* gB1 = Bt + (size_t)(n0 + 64 + trow) * K + tcol;

    const int sw = (l15 >> 1) & 3;

    f32x4 acc[4][4] = {};

    for (int kt = 0; kt < K; kt += 32) {
        __syncthreads();
        gl2lds16(gA0 + kt, ldsA0);
        gl2lds16(gA1 + kt, ldsA0 + 4096);
        gl2lds16(gB0 + kt, ldsB0);
        gl2lds16(gB1 + kt, ldsB0 + 4096);
        __syncthreads();

        bf16x8 af[4], bfr[4];
#pragma unroll
        for (int i = 0; i < 4; i++)
            af[i] = *(const bf16x8*)((const char*)As +
                     (wr * 64 + i * 16 + l15) * 64 + ((quad ^ sw) * 16));
#pragma unroll
        for (int i = 0; i < 4; i++)
            bfr[i] = *(const bf16x8*)((const char*)Bs +
                     (wc * 64 + i * 16 + l15) * 64 + ((quad ^ sw) * 16));
#pragma unroll
        for (int fr = 0; fr < 4; fr++)
#pragma unroll
            for (int fc = 0; fc < 4; fc++)
                acc[fr][fc] = mfma_bf16(af[fr], bfr[fc], acc[fr][fc]);
    }

#pragma unroll
    for (int fr = 0; fr < 4; fr++) {
        int row = m0 + wr * 64 + fr * 16 + quad * 4;
#pragma unroll
        for (int fc = 0; fc < 4; fc++) {
            int col = n0 + wc * 64 + fc * 16 + l15;
            float bv = bias[col];
#pragma unroll
            for (int r = 0; r < 4; r++) {
                float v = (acc[fr][fc][r] + bv) * alpha;
                if (F32OUT)
                    ((float*)Cout)[(size_t)(row + r) * N + col] = v;
                else
                    ((bf16*)Cout)[(size_t)(row + r) * N + col] = (bf16)v;
            }
        }
    }
}

// ---------------------------------------------------------------- V^T GEMM
// Vt[i][j] = Wvt[i][:] . yb[j][:] + bv[i]; per-head layout Vt[(b*16+h)*64+d][s].
__global__ __launch_bounds__(256, 3) void gemm_vt(const bf16* __restrict__ Wvt,
                                                  const bf16* __restrict__ Yb,
                                                  const float* __restrict__ bias,
                                                  bf16* __restrict__ Vt) {
    const int K = DCROSS;
    __shared__ bf16 As[128 * 32];
    __shared__ bf16 Bs[128 * 32];
    const int tid  = threadIdx.x;
    const int wave = tid >> 6, lane = tid & 63;
    const int quad = lane >> 4, l15 = lane & 15;
    const int m0 = blockIdx.x * 128;   // embed block
    const int n0 = blockIdx.y * 128;   // seq block
    const int wr = wave >> 1, wc = wave & 1;

    const int trow = tid >> 2;
    const int tcol = ((tid & 3) ^ ((tid >> 3) & 3)) * 8;
    char* ldsA0 = (char*)As + wave * 1024;
    char* ldsB0 = (char*)Bs + wave * 1024;
    const bf16* gA0 = Wvt + (size_t)(m0 + trow) * K + tcol;
    const bf16* gA1 = Wvt + (size_t)(m0 + 64 + trow) * K + tcol;
    const bf16* gB0 = Yb + (size_t)(n0 + trow) * K + tcol;
    const bf16* gB1 = Yb + (size_t)(n0 + 64 + trow) * K + tcol;

    const int sw = (l15 >> 1) & 3;

    f32x4 acc[4][4] = {};

    for (int kt = 0; kt < K; kt += 32) {
        __syncthreads();
        gl2lds16(gA0 + kt, ldsA0);
        gl2lds16(gA1 + kt, ldsA0 + 4096);
        gl2lds16(gB0 + kt, ldsB0);
        gl2lds16(gB1 + kt, ldsB0 + 4096);
        __syncthreads();

        bf16x8 af[4], bfr[4];
#pragma unroll
        for (int i = 0; i < 4; i++)
            af[i] = *(const bf16x8*)((const char*)As +
                     (wr * 64 + i * 16 + l15) * 64 + ((quad ^ sw) * 16));
#pragma unroll
        for (int i = 0; i < 4; i++)
            bfr[i] = *(const bf16x8*)((const char*)Bs +
                     (wc * 64 + i * 16 + l15) * 64 + ((quad ^ sw) * 16));
#pragma unroll
        for (int fr = 0; fr < 4; fr++)
#pragma unroll
            for (int fc = 0; fc < 4; fc++)
                acc[fr][fc] = mfma_bf16(af[fr], bfr[fc], acc[fr][fc]);
    }

    const int b = n0 >> 11;
    const size_t bbase = (size_t)b * DEMBED * SLEN;
#pragma unroll
    for (int fr = 0; fr < 4; fr++) {
        int row = m0 + wr * 64 + fr * 16 + quad * 4;
#pragma unroll
        for (int fc = 0; fc < 4; fc++) {
            int col = n0 + wc * 64 + fc * 16 + l15;
            int s = col & (SLEN - 1);
#pragma unroll
            for (int r = 0; r < 4; r++) {
                float v = acc[fr][fc][r] + bias[row + r];
                Vt[bbase + (size_t)(row + r) * SLEN + s] = (bf16)v;
            }
        }
    }
}

// ---------------------------------------------------------------- attention v4
// Block: 256 thr (4 waves), 256 q rows (64/wave), one (b,h). 64-key tiles.
// rg=4 doubles q per wave vs v3 -> K/V LDS fragment reads amortized over 2x
// work (attn was LDS-BW-bound). S^T = K Q^T (packed P writes), shift-free
// softmax, scale*log2e pre-folded into Q.
__global__ __launch_bounds__(256, 2) void attn(const bf16* __restrict__ Q,
                                               const bf16* __restrict__ K,
                                               const bf16* __restrict__ Vt,
                                               bf16* __restrict__ O) {
    __shared__ bf16 KsA[64 * 64];        // [key][d]   XOR-swizzled chunks
    __shared__ bf16 VsA[64 * 64];        // [d][key]   XOR-swizzled chunks
    __shared__ bf16 PsA[4 * 64 * 72];    // per-wave [q][key], pad 72

    const int tid  = threadIdx.x;
    const int wave = tid >> 6, lane = tid & 63;
    const int quad = lane >> 4, l15 = lane & 15;
    const int bh = blockIdx.y, b = bh >> 4, h = bh & 15;
    const size_t rowbase = (size_t)b * SLEN;
    const int qb = blockIdx.x * 256 + wave * 64;
    const int hc = h * DHEAD;

    // Q fragments (pre-scaled by 0.125*log2e in projection)
    bf16x8 qf[4][2];
#pragma unroll
    for (int rg = 0; rg < 4; rg++)
#pragma unroll
        for (int kg = 0; kg < 2; kg++)
            qf[rg][kg] = *(const bf16x8*)(Q + (rowbase + qb + rg * 16 + l15) * DEMBED
                                          + hc + kg * 32 + quad * 8);

    f32x4 o[4][4] = {};
    f32x4 lsv[4] = {};

    const bf16* Kbase = K + rowbase * DEMBED + hc;
    const bf16* Vbase = Vt + (size_t)bh * DHEAD * SLEN;

    const int xcol = (((tid & 7) ^ ((tid >> 3) & 7)) * 8);
    const bf16* gK = Kbase + (size_t)(tid >> 3) * DEMBED + xcol;
    const bf16* gV = Vbase + (size_t)(tid >> 3) * SLEN + xcol;
    char* ldsK = (char*)KsA + wave * 1024;
    char* ldsV = (char*)VsA + wave * 1024;
    bf16* Pw = PsA + wave * (64 * 72);

    for (int kb = 0; kb < SLEN; kb += 64) {
        __syncthreads();
        gl2lds16(gK + (size_t)kb * DEMBED, ldsK);
        gl2lds16(gK + (size_t)(kb + 32) * DEMBED, ldsK + 32 * 128);
        gl2lds16(gV + kb, ldsV);
        gl2lds16(gV + 32 * SLEN + kb, ldsV + 32 * 128);
        __syncthreads();

        // S^T per column-group: q = rg*16+l15, key = cg*16+quad*4+r
#pragma unroll
        for (int cg = 0; cg < 4; cg++) {
            f32x4 s[4] = {};
#pragma unroll
            for (int kg = 0; kg < 2; kg++) {
                bf16x8 kf = *(const bf16x8*)((const char*)KsA +
                            (cg * 16 + l15) * 128 + (((kg * 4 + quad) ^ (l15 & 7)) * 16));
#pragma unroll
                for (int rg = 0; rg < 4; rg++)
                    s[rg] = mfma_bf16(kf, qf[rg][kg], s[rg]);
            }
#pragma unroll
            for (int rg = 0; rg < 4; rg++) {
                f32x4 p;
                p[0] = __builtin_amdgcn_exp2f(s[rg][0]);
                p[1] = __builtin_amdgcn_exp2f(s[rg][1]);
                p[2] = __builtin_amdgcn_exp2f(s[rg][2]);
                p[3] = __builtin_amdgcn_exp2f(s[rg][3]);
                lsv[rg] += p;
                bf16x4 pb = { (bf16)p[0], (bf16)p[1], (bf16)p[2], (bf16)p[3] };
                *(bf16x4*)(Pw + (rg * 16 + l15) * 72 + cg * 16 + quad * 4) = pb;
            }
        }

        // P V  (Ps per-wave: in-wave LDS ordering, no barrier)
#pragma unroll
        for (int dg = 0; dg < 4; dg++)
#pragma unroll
            for (int kg = 0; kg < 2; kg++) {
                bf16x8 vf = *(const bf16x8*)((const char*)VsA +
                            (dg * 16 + l15) * 128 + (((kg * 4 + quad) ^ (l15 & 7)) * 16));
#pragma unroll
                for (int rg = 0; rg < 4; rg++)
                    o[rg][dg] = mfma_bf16(
                        *(const bf16x8*)(Pw + (rg * 16 + l15) * 72 + kg * 32 + quad * 8),
                        vf, o[rg][dg]);
            }
    }

    // row sums: lane partial for q = rg*16+l15 over key-subset; reduce quads
    float inv[4];
#pragma unroll
    for (int rg = 0; rg < 4; rg++) {
        float rs = lsv[rg][0] + lsv[rg][1] + lsv[rg][2] + lsv[rg][3];
        rs += __shfl_xor(rs, 16);
        rs += __shfl_xor(rs, 32);
        inv[rg] = 1.0f / rs;
    }
#pragma unroll
    for (int rg = 0; rg < 4; rg++)
#pragma unroll
        for (int r = 0; r < 4; r++) {
            float iv = __shfl(inv[rg], quad * 4 + r);   // inv for q = rg*16+quad*4+r
#pragma unroll
            for (int dg = 0; dg < 4; dg++)
                O[(rowbase + qb + rg * 16 + quad * 4 + r) * DEMBED + hc + dg * 16 + l15] =
                    (bf16)(o[rg][dg][r] * iv);
        }
}

// ---------------------------------------------------------------- launch
extern "C" void kernel_launch(void* const* d_in, const int* in_sizes, int n_in,
                              void* d_out, int out_size, void* d_ws, size_t ws_size,
                              hipStream_t stream) {
    const float* x  = (const float*)d_in[0];
    const float* y  = (const float*)d_in[1];
    const float* Wq = (const float*)d_in[2];
    const float* bq = (const float*)d_in[3];
    const float* Wk = (const float*)d_in[4];
    const float* bk = (const float*)d_in[5];
    const float* Wv = (const float*)d_in[6];
    const float* bv = (const float*)d_in[7];
    const float* Wo = (const float*)d_in[8];
    const float* bo = (const float*)d_in[9];
    float* out = (float*)d_out;

    char* ws = (char*)d_ws;
    size_t off = 0;
    auto alloc = [&](size_t bytes) {
        void* p = ws + off;
        off += (bytes + 255) & ~(size_t)255;
        return p;
    };
    bf16* xb  = (bf16*)alloc((size_t)MROWS * DEMBED * 2);
    bf16* yb  = (bf16*)alloc((size_t)MROWS * DCROSS * 2);
    bf16* Wqt = (bf16*)alloc((size_t)DEMBED * DEMBED * 2);
    bf16* Wkt = (bf16*)alloc((size_t)DEMBED * DCROSS * 2);
    bf16* Wvt = (bf16*)alloc((size_t)DEMBED * DCROSS * 2);
    bf16* Wot = (bf16*)alloc((size_t)DEMBED * DEMBED * 2);
    bf16* Qb  = (bf16*)alloc((size_t)MROWS * DEMBED * 2);
    bf16* Kb  = (bf16*)alloc((size_t)MROWS * DEMBED * 2);
    bf16* Vtb = (bf16*)alloc((size_t)MROWS * DEMBED * 2);  // V^T per head
    bf16* Ab  = (bf16*)alloc((size_t)MROWS * DEMBED * 2);
    if (off > ws_size) return;

    {
        int n4 = MROWS * DEMBED / 4 + MROWS * DCROSS / 4;
        cvt_xy<<<(n4 + 255) / 256, 256, 0, stream>>>(x, y, xb, yb);
    }
    {
        TrArgs a;
        a.src[0] = Wq;  a.dst[0] = Wqt; a.K[0] = DEMBED;
        a.src[1] = Wk;  a.dst[1] = Wkt; a.K[1] = DCROSS;
        a.src[2] = Wv;  a.dst[2] = Wvt; a.K[2] = DCROSS;
        a.src[3] = Wo;  a.dst[3] = Wot; a.K[3] = DEMBED;
        transpose_all<<<dim3(32, 32, 4), dim3(32, 8), 0, stream>>>(a);
    }

    const float qscale = 0.125f * 1.4426950408889634f;  // 1/sqrt(64) * log2(e)
    dim3 gg(MROWS / 128, DEMBED / 128);
    gemm_bt<false><<<gg, 256, 0, stream>>>(xb, Wqt, bq, Qb, MROWS, DEMBED, DEMBED, qscale);
    gemm_bt<false><<<gg, 256, 0, stream>>>(yb, Wkt, bk, Kb, MROWS, DEMBED, DCROSS, 1.0f);
    gemm_vt<<<dim3(DEMBED / 128, MROWS / 128), 256, 0, stream>>>(Wvt, yb, bv, Vtb);

    attn<<<dim3(SLEN / 256, BATCH * NHEADS), 256, 0, stream>>>(Qb, Kb, Vtb, Ab);

    gemm_bt<true><<<gg, 256, 0, stream>>>(Ab, Wot, bo, out, MROWS, DEMBED, DEMBED, 1.0f);
}

// Round 5
// 303.218 us; speedup vs baseline: 1.0168x; 1.0168x over previous
//
#include <hip/hip_runtime.h>

#define NHEADS 16
#define DEMBED 1024
#define DCROSS 768
#define DHEAD  64
#define BATCH  4
#define SLEN   2048
#define MROWS  (BATCH * SLEN)   // 8192

using bf16   = __bf16;
using bf16x8 = __attribute__((ext_vector_type(8))) __bf16;
using bf16x4 = __attribute__((ext_vector_type(4))) __bf16;
using f32x4  = __attribute__((ext_vector_type(4))) float;

__device__ __forceinline__ f32x4 mfma_bf16(bf16x8 a, bf16x8 b, f32x4 c) {
    return __builtin_amdgcn_mfma_f32_16x16x32_bf16(a, b, c, 0, 0, 0);
}

// async global->LDS, 16B per lane; lds dest = wave-uniform base + lane*16
__device__ __forceinline__ void gl2lds16(const void* g, void* l) {
    __builtin_amdgcn_global_load_lds(
        (const __attribute__((address_space(1))) void*)g,
        (__attribute__((address_space(3))) void*)l, 16, 0, 0);
}

// ---------------------------------------------------------------- prep (fused)
__global__ void cvt_xy(const float* __restrict__ x, const float* __restrict__ y,
                       bf16* __restrict__ xb, bf16* __restrict__ yb) {
    const int n4x = MROWS * DEMBED / 4;
    const int n4y = MROWS * DCROSS / 4;
    int i = blockIdx.x * blockDim.x + threadIdx.x;
    const float* src;
    bf16* dst;
    int j;
    if (i < n4x) { src = x; dst = xb; j = i; }
    else { j = i - n4x; if (j >= n4y) return; src = y; dst = yb; }
    float4 v = ((const float4*)src)[j];
    bf16x4 o = { (bf16)v.x, (bf16)v.y, (bf16)v.z, (bf16)v.w };
    ((bf16x4*)dst)[j] = o;
}

struct TrArgs { const float* src[4]; bf16* dst[4]; int K[4]; };
__global__ void transpose_all(TrArgs a) {
    __shared__ float tile[32][33];
    const int which = blockIdx.z;
    const int K = a.K[which];
    const int N = DEMBED;
    int n0 = blockIdx.x * 32, k0 = blockIdx.y * 32;
    if (k0 >= K) return;
    const float* W = a.src[which];
    bf16* Wt = a.dst[which];
    int tx = threadIdx.x, ty = threadIdx.y;
#pragma unroll
    for (int i = 0; i < 32; i += 8)
        tile[ty + i][tx] = W[(size_t)(k0 + ty + i) * N + n0 + tx];
    __syncthreads();
#pragma unroll
    for (int i = 0; i < 32; i += 8)
        Wt[(size_t)(n0 + ty + i) * K + k0 + tx] = (bf16)tile[tx][ty + i];
}

// ---------------------------------------------------------------- fused QKV GEMM
// 1536 blocks: [0,512) Q = xb@Wqt^T (*qscale), [512,1024) K = yb@Wkt^T,
// [1024,1536) V^T = Wvt@yb^T written per-head transposed.
// 128x128 tile, BK=32, global_load_lds staging, XOR-swizzled LDS.
struct QkvArgs {
    const bf16 *xb, *yb, *Wqt, *Wkt, *Wvt;
    const float *bq, *bk, *bv;
    bf16 *Qb, *Kb, *Vt;
    float qscale;
};
__global__ __launch_bounds__(256, 3) void gemm_qkv(QkvArgs a) {
    __shared__ bf16 As[128 * 32];
    __shared__ bf16 Bs[128 * 32];
    const int id = blockIdx.x;
    const int cls = id >> 9;   // 0=Q 1=K 2=V
    const bf16 *A, *Bt;
    const float* bias;
    int K, m0, n0;
    if (cls == 0) { int t = id;        m0 = (t >> 3) * 128; n0 = (t & 7) * 128;
                    A = a.xb;  Bt = a.Wqt; bias = a.bq; K = DEMBED; }
    else if (cls == 1) { int t = id - 512;  m0 = (t >> 3) * 128; n0 = (t & 7) * 128;
                    A = a.yb;  Bt = a.Wkt; bias = a.bk; K = DCROSS; }
    else { int t = id - 1024; m0 = (t >> 6) * 128; n0 = (t & 63) * 128;
                    A = a.Wvt; Bt = a.yb;  bias = a.bv; K = DCROSS; }

    const int tid  = threadIdx.x;
    const int wave = tid >> 6, lane = tid & 63;
    const int quad = lane >> 4, l15 = lane & 15;
    const int wr = wave >> 1, wc = wave & 1;

    const int trow = tid >> 2;
    const int tcol = ((tid & 3) ^ ((tid >> 3) & 3)) * 8;
    char* ldsA0 = (char*)As + wave * 1024;
    char* ldsB0 = (char*)Bs + wave * 1024;
    const bf16* gA0 = A + (size_t)(m0 + trow) * K + tcol;
    const bf16* gA1 = A + (size_t)(m0 + 64 + trow) * K + tcol;
    const bf16* gB0 = Bt + (size_t)(n0 + trow) * K + tcol;
    const bf16* gB1 = Bt + (size_t)(n0 + 64 + trow) * K + tcol;

    const int sw = (l15 >> 1) & 3;

    f32x4 acc[4][4] = {};

    for (int kt = 0; kt < K; kt += 32) {
        __syncthreads();
        gl2lds16(gA0 + kt, ldsA0);
        gl2lds16(gA1 + kt, ldsA0 + 4096);
        gl2lds16(gB0 + kt, ldsB0);
        gl2lds16(gB1 + kt, ldsB0 + 4096);
        __syncthreads();

        bf16x8 af[4], bfr[4];
#pragma unroll
        for (int i = 0; i < 4; i++)
            af[i] = *(const bf16x8*)((const char*)As +
                     (wr * 64 + i * 16 + l15) * 64 + ((quad ^ sw) * 16));
#pragma unroll
        for (int i = 0; i < 4; i++)
            bfr[i] = *(const bf16x8*)((const char*)Bs +
                     (wc * 64 + i * 16 + l15) * 64 + ((quad ^ sw) * 16));
#pragma unroll
        for (int fr = 0; fr < 4; fr++)
#pragma unroll
            for (int fc = 0; fc < 4; fc++)
                acc[fr][fc] = mfma_bf16(af[fr], bfr[fc], acc[fr][fc]);
    }

    if (cls < 2) {
        bf16* Cout = (cls == 0) ? a.Qb : a.Kb;
        const float alpha = (cls == 0) ? a.qscale : 1.0f;
#pragma unroll
        for (int fr = 0; fr < 4; fr++) {
            int row = m0 + wr * 64 + fr * 16 + quad * 4;
#pragma unroll
            for (int fc = 0; fc < 4; fc++) {
                int col = n0 + wc * 64 + fc * 16 + l15;
                float bv = bias[col];
#pragma unroll
                for (int r = 0; r < 4; r++)
                    Cout[(size_t)(row + r) * DEMBED + col] =
                        (bf16)((acc[fr][fc][r] + bv) * alpha);
            }
        }
    } else {
        const int b = n0 >> 11;
        const size_t bbase = (size_t)b * DEMBED * SLEN;
#pragma unroll
        for (int fr = 0; fr < 4; fr++) {
            int row = m0 + wr * 64 + fr * 16 + quad * 4;   // embed index
#pragma unroll
            for (int fc = 0; fc < 4; fc++) {
                int col = n0 + wc * 64 + fc * 16 + l15;
                int s = col & (SLEN - 1);
#pragma unroll
                for (int r = 0; r < 4; r++)
                    a.Vt[bbase + (size_t)(row + r) * SLEN + s] =
                        (bf16)(acc[fr][fc][r] + bias[row + r]);
            }
        }
    }
}

// ---------------------------------------------------------------- O GEMM
// out[M,N] f32 = Ab@Wot^T + bo. 128x64 tiles -> 1024 blocks (4/CU).
// 4 waves stacked along m, wave tile 32x64 (2x4 frags).
__global__ __launch_bounds__(256, 4) void gemm_o(const bf16* __restrict__ A,
                                                 const bf16* __restrict__ Bt,
                                                 const float* __restrict__ bias,
                                                 float* __restrict__ Cout) {
    const int K = DEMBED, N = DEMBED;
    __shared__ bf16 As[128 * 32];
    __shared__ bf16 Bs[64 * 32];
    const int tid  = threadIdx.x;
    const int wave = tid >> 6, lane = tid & 63;
    const int quad = lane >> 4, l15 = lane & 15;
    const int m0 = blockIdx.x * 128, n0 = blockIdx.y * 64;

    const int trow = tid >> 2;
    const int tcol = ((tid & 3) ^ ((tid >> 3) & 3)) * 8;
    char* ldsA0 = (char*)As + wave * 1024;
    char* ldsB0 = (char*)Bs + wave * 1024;
    const bf16* gA0 = A + (size_t)(m0 + trow) * K + tcol;
    const bf16* gA1 = A + (size_t)(m0 + 64 + trow) * K + tcol;
    const bf16* gB0 = Bt + (size_t)(n0 + trow) * K + tcol;

    const int sw = (l15 >> 1) & 3;

    f32x4 acc[2][4] = {};

    for (int kt = 0; kt < K; kt += 32) {
        __syncthreads();
        gl2lds16(gA0 + kt, ldsA0);
        gl2lds16(gA1 + kt, ldsA0 + 4096);
        gl2lds16(gB0 + kt, ldsB0);
        __syncthreads();

        bf16x8 af[2], bfr[4];
#pragma unroll
        for (int i = 0; i < 2; i++)
            af[i] = *(const bf16x8*)((const char*)As +
                     (wave * 32 + i * 16 + l15) * 64 + ((quad ^ sw) * 16));
#pragma unroll
        for (int i = 0; i < 4; i++)
            bfr[i] = *(const bf16x8*)((const char*)Bs +
                     (i * 16 + l15) * 64 + ((quad ^ sw) * 16));
#pragma unroll
        for (int fr = 0; fr < 2; fr++)
#pragma unroll
            for (int fc = 0; fc < 4; fc++)
                acc[fr][fc] = mfma_bf16(af[fr], bfr[fc], acc[fr][fc]);
    }

#pragma unroll
    for (int fr = 0; fr < 2; fr++) {
        int row = m0 + wave * 32 + fr * 16 + quad * 4;
#pragma unroll
        for (int fc = 0; fc < 4; fc++) {
            int col = n0 + fc * 16 + l15;
            float bv = bias[col];
#pragma unroll
            for (int r = 0; r < 4; r++)
                Cout[(size_t)(row + r) * N + col] = acc[fr][fc][r] + bv;
        }
    }
}

// ---------------------------------------------------------------- attention (round-3 config)
// Block: 256 thr (4 waves), 128 q rows (32/wave), one (b,h). 64-key tiles.
// S^T = K Q^T (packed P writes), shift-free softmax, scale*log2e folded into Q.
__global__ __launch_bounds__(256, 4) void attn(const bf16* __restrict__ Q,
                                               const bf16* __restrict__ K,
                                               const bf16* __restrict__ Vt,
                                               bf16* __restrict__ O) {
    __shared__ bf16 KsA[64 * 64];        // [key][d]   XOR-swizzled chunks
    __shared__ bf16 VsA[64 * 64];        // [d][key]   XOR-swizzled chunks
    __shared__ bf16 PsA[4 * 32 * 72];    // per-wave [q][key], pad 72

    const int tid  = threadIdx.x;
    const int wave = tid >> 6, lane = tid & 63;
    const int quad = lane >> 4, l15 = lane & 15;
    const int bh = blockIdx.y, b = bh >> 4, h = bh & 15;
    const size_t rowbase = (size_t)b * SLEN;
    const int qb = blockIdx.x * 128 + wave * 32;
    const int hc = h * DHEAD;

    bf16x8 qf[2][2];
#pragma unroll
    for (int rg = 0; rg < 2; rg++)
#pragma unroll
        for (int kg = 0; kg < 2; kg++)
            qf[rg][kg] = *(const bf16x8*)(Q + (rowbase + qb + rg * 16 + l15) * DEMBED
                                          + hc + kg * 32 + quad * 8);

    f32x4 o[2][4] = {};
    f32x4 lsv[2] = {};

    const bf16* Kbase = K + rowbase * DEMBED + hc;
    const bf16* Vbase = Vt + (size_t)bh * DHEAD * SLEN;

    const int xcol = (((tid & 7) ^ ((tid >> 3) & 7)) * 8);
    const bf16* gK = Kbase + (size_t)(tid >> 3) * DEMBED + xcol;
    const bf16* gV = Vbase + (size_t)(tid >> 3) * SLEN + xcol;
    char* ldsK = (char*)KsA + wave * 1024;
    char* ldsV = (char*)VsA + wave * 1024;
    bf16* Pw = PsA + wave * (32 * 72);

    for (int kb = 0; kb < SLEN; kb += 64) {
        __syncthreads();
        gl2lds16(gK + (size_t)kb * DEMBED, ldsK);
        gl2lds16(gK + (size_t)(kb + 32) * DEMBED, ldsK + 32 * 128);
        gl2lds16(gV + kb, ldsV);
        gl2lds16(gV + 32 * SLEN + kb, ldsV + 32 * 128);
        __syncthreads();

        f32x4 s[2][4] = {};
#pragma unroll
        for (int cg = 0; cg < 4; cg++)
#pragma unroll
            for (int kg = 0; kg < 2; kg++) {
                bf16x8 kf = *(const bf16x8*)((const char*)KsA +
                            (cg * 16 + l15) * 128 + (((kg * 4 + quad) ^ (l15 & 7)) * 16));
#pragma unroll
                for (int rg = 0; rg < 2; rg++)
                    s[rg][cg] = mfma_bf16(kf, qf[rg][kg], s[rg][cg]);
            }

#pragma unroll
        for (int rg = 0; rg < 2; rg++)
#pragma unroll
            for (int cg = 0; cg < 4; cg++) {
                f32x4 p;
                p[0] = __builtin_amdgcn_exp2f(s[rg][cg][0]);
                p[1] = __builtin_amdgcn_exp2f(s[rg][cg][1]);
                p[2] = __builtin_amdgcn_exp2f(s[rg][cg][2]);
                p[3] = __builtin_amdgcn_exp2f(s[rg][cg][3]);
                lsv[rg] += p;
                bf16x4 pb = { (bf16)p[0], (bf16)p[1], (bf16)p[2], (bf16)p[3] };
                *(bf16x4*)(Pw + (rg * 16 + l15) * 72 + cg * 16 + quad * 4) = pb;
            }

#pragma unroll
        for (int dg = 0; dg < 4; dg++)
#pragma unroll
            for (int kg = 0; kg < 2; kg++) {
                bf16x8 vf = *(const bf16x8*)((const char*)VsA +
                            (dg * 16 + l15) * 128 + (((kg * 4 + quad) ^ (l15 & 7)) * 16));
#pragma unroll
                for (int rg = 0; rg < 2; rg++)
                    o[rg][dg] = mfma_bf16(
                        *(const bf16x8*)(Pw + (rg * 16 + l15) * 72 + kg * 32 + quad * 8),
                        vf, o[rg][dg]);
            }
    }

    float inv[2];
#pragma unroll
    for (int rg = 0; rg < 2; rg++) {
        float rs = lsv[rg][0] + lsv[rg][1] + lsv[rg][2] + lsv[rg][3];
        rs += __shfl_xor(rs, 16);
        rs += __shfl_xor(rs, 32);
        inv[rg] = 1.0f / rs;
    }
#pragma unroll
    for (int rg = 0; rg < 2; rg++)
#pragma unroll
        for (int r = 0; r < 4; r++) {
            float iv = __shfl(inv[rg], quad * 4 + r);
#pragma unroll
            for (int dg = 0; dg < 4; dg++)
                O[(rowbase + qb + rg * 16 + quad * 4 + r) * DEMBED + hc + dg * 16 + l15] =
                    (bf16)(o[rg][dg][r] * iv);
        }
}

// ---------------------------------------------------------------- launch
extern "C" void kernel_launch(void* const* d_in, const int* in_sizes, int n_in,
                              void* d_out, int out_size, void* d_ws, size_t ws_size,
                              hipStream_t stream) {
    const float* x  = (const float*)d_in[0];
    const float* y  = (const float*)d_in[1];
    const float* Wq = (const float*)d_in[2];
    const float* bq = (const float*)d_in[3];
    const float* Wk = (const float*)d_in[4];
    const float* bk = (const float*)d_in[5];
    const float* Wv = (const float*)d_in[6];
    const float* bv = (const float*)d_in[7];
    const float* Wo = (const float*)d_in[8];
    const float* bo = (const float*)d_in[9];
    float* out = (float*)d_out;

    char* ws = (char*)d_ws;
    size_t off = 0;
    auto alloc = [&](size_t bytes) {
        void* p = ws + off;
        off += (bytes + 255) & ~(size_t)255;
        return p;
    };
    bf16* xb  = (bf16*)alloc((size_t)MROWS * DEMBED * 2);
    bf16* yb  = (bf16*)alloc((size_t)MROWS * DCROSS * 2);
    bf16* Wqt = (bf16*)alloc((size_t)DEMBED * DEMBED * 2);
    bf16* Wkt = (bf16*)alloc((size_t)DEMBED * DCROSS * 2);
    bf16* Wvt = (bf16*)alloc((size_t)DEMBED * DCROSS * 2);
    bf16* Wot = (bf16*)alloc((size_t)DEMBED * DEMBED * 2);
    bf16* Qb  = (bf16*)alloc((size_t)MROWS * DEMBED * 2);
    bf16* Kb  = (bf16*)alloc((size_t)MROWS * DEMBED * 2);
    bf16* Vtb = (bf16*)alloc((size_t)MROWS * DEMBED * 2);  // V^T per head
    bf16* Ab  = (bf16*)alloc((size_t)MROWS * DEMBED * 2);
    if (off > ws_size) return;

    {
        int n4 = MROWS * DEMBED / 4 + MROWS * DCROSS / 4;
        cvt_xy<<<(n4 + 255) / 256, 256, 0, stream>>>(x, y, xb, yb);
    }
    {
        TrArgs a;
        a.src[0] = Wq;  a.dst[0] = Wqt; a.K[0] = DEMBED;
        a.src[1] = Wk;  a.dst[1] = Wkt; a.K[1] = DCROSS;
        a.src[2] = Wv;  a.dst[2] = Wvt; a.K[2] = DCROSS;
        a.src[3] = Wo;  a.dst[3] = Wot; a.K[3] = DEMBED;
        transpose_all<<<dim3(32, 32, 4), dim3(32, 8), 0, stream>>>(a);
    }

    {
        QkvArgs a;
        a.xb = xb; a.yb = yb; a.Wqt = Wqt; a.Wkt = Wkt; a.Wvt = Wvt;
        a.bq = bq; a.bk = bk; a.bv = bv;
        a.Qb = Qb; a.Kb = Kb; a.Vt = Vtb;
        a.qscale = 0.125f * 1.4426950408889634f;   // 1/sqrt(64) * log2(e)
        gemm_qkv<<<1536, 256, 0, stream>>>(a);
    }

    attn<<<dim3(SLEN / 128, BATCH * NHEADS), 256, 0, stream>>>(Qb, Kb, Vtb, Ab);

    gemm_o<<<dim3(MROWS / 128, DEMBED / 64), 256, 0, stream>>>(Ab, Wot, bo, out);
}

// Round 6
// 286.391 us; speedup vs baseline: 1.0765x; 1.0588x over previous
//
#include <hip/hip_runtime.h>

#define NHEADS 16
#define DEMBED 1024
#define DCROSS 768
#define DHEAD  64
#define BATCH  4
#define SLEN   2048
#define MROWS  (BATCH * SLEN)   // 8192

using bf16   = __bf16;
using bf16x8 = __attribute__((ext_vector_type(8))) __bf16;
using bf16x4 = __attribute__((ext_vector_type(4))) __bf16;
using f32x4  = __attribute__((ext_vector_type(4))) float;

__device__ __forceinline__ f32x4 mfma_bf16(bf16x8 a, bf16x8 b, f32x4 c) {
    return __builtin_amdgcn_mfma_f32_16x16x32_bf16(a, b, c, 0, 0, 0);
}

// async global->LDS, 16B per lane; lds dest = wave-uniform base + lane*16
__device__ __forceinline__ void gl2lds16(const void* g, void* l) {
    __builtin_amdgcn_global_load_lds(
        (const __attribute__((address_space(1))) void*)g,
        (__attribute__((address_space(3))) void*)l, 16, 0, 0);
}

// ---------------------------------------------------------------- prep (one kernel)
// blocks [0,4096): weight transposes; [4096, 4096+14336): x/y f32->bf16 cvt.
struct PrepArgs {
    const float* wsrc[4]; bf16* wdst[4]; int wK[4];
    const float *x, *y; bf16 *xb, *yb;
};
#define NTRB 4096
__global__ void prep_all(PrepArgs a) {
    const int bid = blockIdx.x;
    const int tid = threadIdx.x;
    if (bid < NTRB) {
        __shared__ float tile[32][33];
        const int which = bid >> 10, rem = bid & 1023;
        const int K = a.wK[which], N = DEMBED;
        const int n0 = (rem & 31) * 32, k0 = (rem >> 5) * 32;
        if (k0 >= K) return;
        const float* W = a.wsrc[which];
        bf16* Wt = a.wdst[which];
        const int tx = tid & 31, ty = tid >> 5;
#pragma unroll
        for (int i = 0; i < 32; i += 8)
            tile[ty + i][tx] = W[(size_t)(k0 + ty + i) * N + n0 + tx];
        __syncthreads();
#pragma unroll
        for (int i = 0; i < 32; i += 8)
            Wt[(size_t)(n0 + ty + i) * K + k0 + tx] = (bf16)tile[tx][ty + i];
    } else {
        const int n4x = MROWS * DEMBED / 4;
        const int n4y = MROWS * DCROSS / 4;
        int i = (bid - NTRB) * 256 + tid;
        const float* src; bf16* dst; int j;
        if (i < n4x) { src = a.x; dst = a.xb; j = i; }
        else { j = i - n4x; if (j >= n4y) return; src = a.y; dst = a.yb; }
        float4 v = ((const float4*)src)[j];
        bf16x4 o = { (bf16)v.x, (bf16)v.y, (bf16)v.z, (bf16)v.w };
        ((bf16x4*)dst)[j] = o;
    }
}

// ---------------------------------------------------------------- fused QKV GEMM
// BK=64: 128x128 tile, 16B async staging, XOR-swizzled LDS, 32 MFMA/barrier-pair.
// blocks: [0,512) Q = xb@Wqt^T (*qscale), [512,1024) K = yb@Wkt^T,
// [1024,1536) V^T = Wvt@yb^T written per-head transposed.
struct QkvArgs {
    const bf16 *xb, *yb, *Wqt, *Wkt, *Wvt;
    const float *bq, *bk, *bv;
    bf16 *Qb, *Kb, *Vt;
    float qscale;
};
__global__ __launch_bounds__(256, 3) void gemm_qkv(QkvArgs a) {
    __shared__ bf16 As[128 * 64];
    __shared__ bf16 Bs[128 * 64];
    const int id = blockIdx.x;
    const int cls = id >> 9;   // 0=Q 1=K 2=V
    const bf16 *A, *Bt;
    const float* bias;
    int K, m0, n0;
    if (cls == 0) { int t = id;        m0 = (t >> 3) * 128; n0 = (t & 7) * 128;
                    A = a.xb;  Bt = a.Wqt; bias = a.bq; K = DEMBED; }
    else if (cls == 1) { int t = id - 512;  m0 = (t >> 3) * 128; n0 = (t & 7) * 128;
                    A = a.yb;  Bt = a.Wkt; bias = a.bk; K = DCROSS; }
    else { int t = id - 1024; m0 = (t >> 6) * 128; n0 = (t & 63) * 128;
                    A = a.Wvt; Bt = a.yb;  bias = a.bv; K = DCROSS; }

    const int tid  = threadIdx.x;
    const int wave = tid >> 6, lane = tid & 63;
    const int quad = lane >> 4, l15 = lane & 15;
    const int wr = wave >> 1, wc = wave & 1;

    // staging: call c covers rows c*32 + wave*8 + (lane>>3); phys chunk lane&7
    // holds logical chunk (lane&7)^(lane>>3)  (row&7 == lane>>3).
    const int srow = wave * 8 + (lane >> 3);
    const int scol = ((lane & 7) ^ (lane >> 3)) * 8;   // logical element col
    char* ldsA0 = (char*)As + wave * 1024;
    char* ldsB0 = (char*)Bs + wave * 1024;
    const bf16* gA0 = A + (size_t)(m0 + srow) * K + scol;
    const bf16* gB0 = Bt + (size_t)(n0 + srow) * K + scol;

    const int sw = l15 & 7;   // read-side swizzle (row & 7)

    f32x4 acc[4][4] = {};

    for (int kt = 0; kt < K; kt += 64) {
        __syncthreads();
#pragma unroll
        for (int c = 0; c < 4; c++)
            gl2lds16(gA0 + (size_t)c * 32 * K + kt, ldsA0 + c * 4096);
#pragma unroll
        for (int c = 0; c < 4; c++)
            gl2lds16(gB0 + (size_t)c * 32 * K + kt, ldsB0 + c * 4096);
        __syncthreads();

#pragma unroll
        for (int kg = 0; kg < 2; kg++) {
            bf16x8 af[4], bfr[4];
#pragma unroll
            for (int i = 0; i < 4; i++)
                af[i] = *(const bf16x8*)((const char*)As +
                         (wr * 64 + i * 16 + l15) * 128 + (((kg * 4 + quad) ^ sw) * 16));
#pragma unroll
            for (int i = 0; i < 4; i++)
                bfr[i] = *(const bf16x8*)((const char*)Bs +
                         (wc * 64 + i * 16 + l15) * 128 + (((kg * 4 + quad) ^ sw) * 16));
#pragma unroll
            for (int fr = 0; fr < 4; fr++)
#pragma unroll
                for (int fc = 0; fc < 4; fc++)
                    acc[fr][fc] = mfma_bf16(af[fr], bfr[fc], acc[fr][fc]);
        }
    }

    if (cls < 2) {
        bf16* Cout = (cls == 0) ? a.Qb : a.Kb;
        const float alpha = (cls == 0) ? a.qscale : 1.0f;
#pragma unroll
        for (int fr = 0; fr < 4; fr++) {
            int row = m0 + wr * 64 + fr * 16 + quad * 4;
#pragma unroll
            for (int fc = 0; fc < 4; fc++) {
                int col = n0 + wc * 64 + fc * 16 + l15;
                float bv = bias[col];
#pragma unroll
                for (int r = 0; r < 4; r++)
                    Cout[(size_t)(row + r) * DEMBED + col] =
                        (bf16)((acc[fr][fc][r] + bv) * alpha);
            }
        }
    } else {
        const int b = n0 >> 11;
        const size_t bbase = (size_t)b * DEMBED * SLEN;
#pragma unroll
        for (int fr = 0; fr < 4; fr++) {
            int row = m0 + wr * 64 + fr * 16 + quad * 4;   // embed index
#pragma unroll
            for (int fc = 0; fc < 4; fc++) {
                int col = n0 + wc * 64 + fc * 16 + l15;
                int s = col & (SLEN - 1);
#pragma unroll
                for (int r = 0; r < 4; r++)
                    a.Vt[bbase + (size_t)(row + r) * SLEN + s] =
                        (bf16)(acc[fr][fc][r] + bias[row + r]);
            }
        }
    }
}

// ---------------------------------------------------------------- O GEMM (BK=64)
__global__ __launch_bounds__(256, 3) void gemm_o(const bf16* __restrict__ A,
                                                 const bf16* __restrict__ Bt,
                                                 const float* __restrict__ bias,
                                                 float* __restrict__ Cout) {
    const int K = DEMBED, N = DEMBED;
    __shared__ bf16 As[128 * 64];
    __shared__ bf16 Bs[128 * 64];
    const int tid  = threadIdx.x;
    const int wave = tid >> 6, lane = tid & 63;
    const int quad = lane >> 4, l15 = lane & 15;
    const int m0 = blockIdx.x * 128, n0 = blockIdx.y * 128;
    const int wr = wave >> 1, wc = wave & 1;

    const int srow = wave * 8 + (lane >> 3);
    const int scol = ((lane & 7) ^ (lane >> 3)) * 8;
    char* ldsA0 = (char*)As + wave * 1024;
    char* ldsB0 = (char*)Bs + wave * 1024;
    const bf16* gA0 = A + (size_t)(m0 + srow) * K + scol;
    const bf16* gB0 = Bt + (size_t)(n0 + srow) * K + scol;

    const int sw = l15 & 7;

    f32x4 acc[4][4] = {};

    for (int kt = 0; kt < K; kt += 64) {
        __syncthreads();
#pragma unroll
        for (int c = 0; c < 4; c++)
            gl2lds16(gA0 + (size_t)c * 32 * K + kt, ldsA0 + c * 4096);
#pragma unroll
        for (int c = 0; c < 4; c++)
            gl2lds16(gB0 + (size_t)c * 32 * K + kt, ldsB0 + c * 4096);
        __syncthreads();

#pragma unroll
        for (int kg = 0; kg < 2; kg++) {
            bf16x8 af[4], bfr[4];
#pragma unroll
            for (int i = 0; i < 4; i++)
                af[i] = *(const bf16x8*)((const char*)As +
                         (wr * 64 + i * 16 + l15) * 128 + (((kg * 4 + quad) ^ sw) * 16));
#pragma unroll
            for (int i = 0; i < 4; i++)
                bfr[i] = *(const bf16x8*)((const char*)Bs +
                         (wc * 64 + i * 16 + l15) * 128 + (((kg * 4 + quad) ^ sw) * 16));
#pragma unroll
            for (int fr = 0; fr < 4; fr++)
#pragma unroll
                for (int fc = 0; fc < 4; fc++)
                    acc[fr][fc] = mfma_bf16(af[fr], bfr[fc], acc[fr][fc]);
        }
    }

#pragma unroll
    for (int fr = 0; fr < 4; fr++) {
        int row = m0 + wr * 64 + fr * 16 + quad * 4;
#pragma unroll
        for (int fc = 0; fc < 4; fc++) {
            int col = n0 + wc * 64 + fc * 16 + l15;
            float bv = bias[col];
#pragma unroll
            for (int r = 0; r < 4; r++)
                Cout[(size_t)(row + r) * N + col] = acc[fr][fc][r] + bv;
        }
    }
}

// ---------------------------------------------------------------- attention
// grid (bh, qblk): linear id mod 8 == bh mod 8 -> all 16 q-blocks of a head on
// one XCD, K/V (512 KB/head) stay L2-resident. Block: 4 waves, 128 q rows
// (32/wave), 64-key tiles. S^T = K Q^T (packed P), shift-free softmax,
// scale*log2e folded into Q.
__global__ __launch_bounds__(256, 4) void attn(const bf16* __restrict__ Q,
                                               const bf16* __restrict__ K,
                                               const bf16* __restrict__ Vt,
                                               bf16* __restrict__ O) {
    __shared__ bf16 KsA[64 * 64];        // [key][d]   XOR-swizzled chunks
    __shared__ bf16 VsA[64 * 64];        // [d][key]   XOR-swizzled chunks
    __shared__ bf16 PsA[4 * 32 * 72];    // per-wave [q][key], pad 72

    const int tid  = threadIdx.x;
    const int wave = tid >> 6, lane = tid & 63;
    const int quad = lane >> 4, l15 = lane & 15;
    const int bh = blockIdx.x, b = bh >> 4, h = bh & 15;
    const size_t rowbase = (size_t)b * SLEN;
    const int qb = blockIdx.y * 128 + wave * 32;
    const int hc = h * DHEAD;

    bf16x8 qf[2][2];
#pragma unroll
    for (int rg = 0; rg < 2; rg++)
#pragma unroll
        for (int kg = 0; kg < 2; kg++)
            qf[rg][kg] = *(const bf16x8*)(Q + (rowbase + qb + rg * 16 + l15) * DEMBED
                                          + hc + kg * 32 + quad * 8);

    f32x4 o[2][4] = {};
    f32x4 lsv[2] = {};

    const bf16* Kbase = K + rowbase * DEMBED + hc;
    const bf16* Vbase = Vt + (size_t)bh * DHEAD * SLEN;

    const int xcol = (((tid & 7) ^ ((tid >> 3) & 7)) * 8);
    const bf16* gK = Kbase + (size_t)(tid >> 3) * DEMBED + xcol;
    const bf16* gV = Vbase + (size_t)(tid >> 3) * SLEN + xcol;
    char* ldsK = (char*)KsA + wave * 1024;
    char* ldsV = (char*)VsA + wave * 1024;
    bf16* Pw = PsA + wave * (32 * 72);

    for (int kb = 0; kb < SLEN; kb += 64) {
        __syncthreads();
        gl2lds16(gK + (size_t)kb * DEMBED, ldsK);
        gl2lds16(gK + (size_t)(kb + 32) * DEMBED, ldsK + 32 * 128);
        gl2lds16(gV + kb, ldsV);
        gl2lds16(gV + 32 * SLEN + kb, ldsV + 32 * 128);
        __syncthreads();

        f32x4 s[2][4] = {};
#pragma unroll
        for (int cg = 0; cg < 4; cg++)
#pragma unroll
            for (int kg = 0; kg < 2; kg++) {
                bf16x8 kf = *(const bf16x8*)((const char*)KsA +
                            (cg * 16 + l15) * 128 + (((kg * 4 + quad) ^ (l15 & 7)) * 16));
#pragma unroll
                for (int rg = 0; rg < 2; rg++)
                    s[rg][cg] = mfma_bf16(kf, qf[rg][kg], s[rg][cg]);
            }

#pragma unroll
        for (int rg = 0; rg < 2; rg++)
#pragma unroll
            for (int cg = 0; cg < 4; cg++) {
                f32x4 p;
                p[0] = __builtin_amdgcn_exp2f(s[rg][cg][0]);
                p[1] = __builtin_amdgcn_exp2f(s[rg][cg][1]);
                p[2] = __builtin_amdgcn_exp2f(s[rg][cg][2]);
                p[3] = __builtin_amdgcn_exp2f(s[rg][cg][3]);
                lsv[rg] += p;
                bf16x4 pb = { (bf16)p[0], (bf16)p[1], (bf16)p[2], (bf16)p[3] };
                *(bf16x4*)(Pw + (rg * 16 + l15) * 72 + cg * 16 + quad * 4) = pb;
            }

#pragma unroll
        for (int dg = 0; dg < 4; dg++)
#pragma unroll
            for (int kg = 0; kg < 2; kg++) {
                bf16x8 vf = *(const bf16x8*)((const char*)VsA +
                            (dg * 16 + l15) * 128 + (((kg * 4 + quad) ^ (l15 & 7)) * 16));
#pragma unroll
                for (int rg = 0; rg < 2; rg++)
                    o[rg][dg] = mfma_bf16(
                        *(const bf16x8*)(Pw + (rg * 16 + l15) * 72 + kg * 32 + quad * 8),
                        vf, o[rg][dg]);
            }
    }

    float inv[2];
#pragma unroll
    for (int rg = 0; rg < 2; rg++) {
        float rs = lsv[rg][0] + lsv[rg][1] + lsv[rg][2] + lsv[rg][3];
        rs += __shfl_xor(rs, 16);
        rs += __shfl_xor(rs, 32);
        inv[rg] = 1.0f / rs;
    }
#pragma unroll
    for (int rg = 0; rg < 2; rg++)
#pragma unroll
        for (int r = 0; r < 4; r++) {
            float iv = __shfl(inv[rg], quad * 4 + r);
#pragma unroll
            for (int dg = 0; dg < 4; dg++)
                O[(rowbase + qb + rg * 16 + quad * 4 + r) * DEMBED + hc + dg * 16 + l15] =
                    (bf16)(o[rg][dg][r] * iv);
        }
}

// ---------------------------------------------------------------- launch
extern "C" void kernel_launch(void* const* d_in, const int* in_sizes, int n_in,
                              void* d_out, int out_size, void* d_ws, size_t ws_size,
                              hipStream_t stream) {
    const float* x  = (const float*)d_in[0];
    const float* y  = (const float*)d_in[1];
    const float* Wq = (const float*)d_in[2];
    const float* bq = (const float*)d_in[3];
    const float* Wk = (const float*)d_in[4];
    const float* bk = (const float*)d_in[5];
    const float* Wv = (const float*)d_in[6];
    const float* bv = (const float*)d_in[7];
    const float* Wo = (const float*)d_in[8];
    const float* bo = (const float*)d_in[9];
    float* out = (float*)d_out;

    char* ws = (char*)d_ws;
    size_t off = 0;
    auto alloc = [&](size_t bytes) {
        void* p = ws + off;
        off += (bytes + 255) & ~(size_t)255;
        return p;
    };
    bf16* xb  = (bf16*)alloc((size_t)MROWS * DEMBED * 2);
    bf16* yb  = (bf16*)alloc((size_t)MROWS * DCROSS * 2);
    bf16* Wqt = (bf16*)alloc((size_t)DEMBED * DEMBED * 2);
    bf16* Wkt = (bf16*)alloc((size_t)DEMBED * DCROSS * 2);
    bf16* Wvt = (bf16*)alloc((size_t)DEMBED * DCROSS * 2);
    bf16* Wot = (bf16*)alloc((size_t)DEMBED * DEMBED * 2);
    bf16* Qb  = (bf16*)alloc((size_t)MROWS * DEMBED * 2);
    bf16* Kb  = (bf16*)alloc((size_t)MROWS * DEMBED * 2);
    bf16* Vtb = (bf16*)alloc((size_t)MROWS * DEMBED * 2);  // V^T per head
    bf16* Ab  = (bf16*)alloc((size_t)MROWS * DEMBED * 2);
    if (off > ws_size) return;

    {
        PrepArgs a;
        a.wsrc[0] = Wq; a.wdst[0] = Wqt; a.wK[0] = DEMBED;
        a.wsrc[1] = Wk; a.wdst[1] = Wkt; a.wK[1] = DCROSS;
        a.wsrc[2] = Wv; a.wdst[2] = Wvt; a.wK[2] = DCROSS;
        a.wsrc[3] = Wo; a.wdst[3] = Wot; a.wK[3] = DEMBED;
        a.x = x; a.y = y; a.xb = xb; a.yb = yb;
        int ncvt = (MROWS * DEMBED / 4 + MROWS * DCROSS / 4 + 255) / 256;
        prep_all<<<NTRB + ncvt, 256, 0, stream>>>(a);
    }

    {
        QkvArgs a;
        a.xb = xb; a.yb = yb; a.Wqt = Wqt; a.Wkt = Wkt; a.Wvt = Wvt;
        a.bq = bq; a.bk = bk; a.bv = bv;
        a.Qb = Qb; a.Kb = Kb; a.Vt = Vtb;
        a.qscale = 0.125f * 1.4426950408889634f;   // 1/sqrt(64) * log2(e)
        gemm_qkv<<<1536, 256, 0, stream>>>(a);
    }

    attn<<<dim3(BATCH * NHEADS, SLEN / 128), 256, 0, stream>>>(Qb, Kb, Vtb, Ab);

    gemm_o<<<dim3(MROWS / 128, DEMBED / 128), 256, 0, stream>>>(Ab, Wot, bo, out);
}